// Round 3
// baseline (156.230 us; speedup 1.0000x reference)
//
#include <hip/hip_runtime.h>
#include <hip/hip_bf16.h>
#include <math.h>

// Problem constants (from reference setup_inputs)
constexpr int B_  = 8;
constexpr int CIN = 3;
constexpr int C_  = 64;
constexpr int H_  = 256;
constexpr int W_  = 256;
constexpr int TAPS = 9;   // K*K, K=3

typedef float f32x4 __attribute__((ext_vector_type(4)));

// One block per (b, y) row. 256 threads.
// Phase -1: issue L2-warming prefetch of the 3 h rows (all 64 ch) this block
//           will consume in phase 2 -> HBM transfer overlaps phase-1 compute.
// Phase 0: stage w2 transposed in LDS.
// Phase 1: thread x computes kern[0..8](b, y, x) into LDS.
// Phase 2: wave w handles channels [16w, 16w+16); lane handles x0 = 4*lane.
__global__ __launch_bounds__(256, 4)
void hsa_fused(const float* __restrict__ lr,
               const float* __restrict__ hin,
               const float* __restrict__ w1,
               const float* __restrict__ b1,
               const float* __restrict__ w2,
               const float* __restrict__ b2,
               float* __restrict__ out)
{
    __shared__ float kernS[TAPS][W_];   // 9*256*4 = 9 KB
    __shared__ float w2t[C_][12];       // 64*12*4 = 3 KB (rows 16B-aligned)

    const int tid = threadIdx.x;
    const int blk = blockIdx.x;         // 0 .. B_*H_-1
    const int b = blk / H_;
    const int y = blk % H_;

    // ---- phase -1: L2-warm prefetch of h rows y-1..y+1, all 64 channels ----
    // 3 rows x 64 ch x 256 floats = 49152 floats; one dword per 64B line
    // -> 3072 loads / block = 12 per thread. Kept live, consumed after barrier.
    const float* hbase = hin + (size_t)b * C_ * H_ * W_;
    float pfv[12];
    #pragma unroll
    for (int k = 0; k < 12; ++k) {
        const int i  = tid + k * 256;      // 0..3071
        const int r  = i >> 10;            // 0..2
        const int c  = (i >> 4) & 63;      // channel
        const int lx = i & 15;             // line within row
        const int yy = y + r - 1;
        pfv[k] = ((unsigned)yy < (unsigned)H_)
                   ? hbase[((size_t)c * H_ + yy) * W_ + lx * 16]
                   : 0.f;
    }

    // ---- phase 0: transpose w2 [9][64] -> w2t [64][12] ----
    for (int i = tid; i < TAPS * C_; i += 256) {
        const int t = i / C_;
        const int c = i % C_;
        w2t[c][t] = w2[i];
    }
    __syncthreads();

    // ---- phase 1: per-pixel kern ----
    {
        const int x = tid;              // 0..255
        // lr window [cin][row][col], zero-padded
        float win[CIN][3][3];
        #pragma unroll
        for (int ci = 0; ci < CIN; ++ci) {
            #pragma unroll
            for (int r = 0; r < 3; ++r) {
                const int yy = y + r - 1;
                const bool vy = (unsigned)yy < (unsigned)H_;
                const float* row = lr + ((size_t)(b * CIN + ci) * H_ + yy) * W_;
                win[ci][r][0] = (vy && x > 0)       ? row[x - 1] : 0.f;
                win[ci][r][1] = vy                   ? row[x]     : 0.f;
                win[ci][r][2] = (vy && x < W_ - 1)  ? row[x + 1] : 0.f;
            }
        }

        float acc[TAPS];
        #pragma unroll
        for (int t = 0; t < TAPS; ++t) acc[t] = b2[t];

        for (int c = 0; c < C_; ++c) {
            // conv1 (3x3, cin=3): three 9-deep chains instead of one 27-deep
            const float* wc = w1 + c * 27;
            float h0 = b1[c], h1 = 0.f, h2 = 0.f;
            #pragma unroll
            for (int r = 0; r < 3; ++r)
                #pragma unroll
                for (int j = 0; j < 3; ++j) {
                    h0 = fmaf(wc[(0 * 3 + r) * 3 + j], win[0][r][j], h0);
                    h1 = fmaf(wc[(1 * 3 + r) * 3 + j], win[1][r][j], h1);
                    h2 = fmaf(wc[(2 * 3 + r) * 3 + j], win[2][r][j], h2);
                }
            float hsum = fmaxf((h0 + h1) + h2, 0.f);   // ReLU

            // 1x1 conv accumulate (w2t row: LDS broadcast)
            const float4 wa = *(const float4*)&w2t[c][0];
            const float4 wb = *(const float4*)&w2t[c][4];
            const float  w8 = w2t[c][8];
            acc[0] = fmaf(wa.x, hsum, acc[0]);
            acc[1] = fmaf(wa.y, hsum, acc[1]);
            acc[2] = fmaf(wa.z, hsum, acc[2]);
            acc[3] = fmaf(wa.w, hsum, acc[3]);
            acc[4] = fmaf(wb.x, hsum, acc[4]);
            acc[5] = fmaf(wb.y, hsum, acc[5]);
            acc[6] = fmaf(wb.z, hsum, acc[6]);
            acc[7] = fmaf(wb.w, hsum, acc[7]);
            acc[8] = fmaf(w8,  hsum, acc[8]);
        }
        #pragma unroll
        for (int t = 0; t < TAPS; ++t) kernS[t][x] = acc[t];
    }
    __syncthreads();   // compiler drains vmcnt here -> prefetch lands under phase 1

    // consume prefetch results (keep the loads alive, negligible cost)
    {
        float pf = 0.f;
        #pragma unroll
        for (int k = 0; k < 12; ++k) pf += pfv[k];
        asm volatile("" :: "v"(pf));
    }

    // ---- phase 2: sim + gate ----
    const int lane = tid & 63;
    const int wav  = tid >> 6;
    const int x0   = lane * 4;

    float4 kt[TAPS];
    #pragma unroll
    for (int t = 0; t < TAPS; ++t) kt[t] = *(const float4*)&kernS[t][x0];

    #pragma unroll 4
    for (int cc = 0; cc < 16; ++cc) {
        const int c = wav * 16 + cc;
        const float* hb = hin + (size_t)(b * C_ + c) * H_ * W_;

        float4 rowv[3];
        float  lft[3], rgt[3];
        #pragma unroll
        for (int r = 0; r < 3; ++r) {
            const int yy = y + r - 1;
            const bool vy = (unsigned)yy < (unsigned)H_;
            float4 m;
            if (vy) m = *(const float4*)(hb + (size_t)yy * W_ + x0);
            else    m = make_float4(0.f, 0.f, 0.f, 0.f);
            rowv[r] = m;
            // column halo via cross-lane shuffle: one wave spans the full row
            float l  = __shfl_up(m.w, 1);
            float rr = __shfl_down(m.x, 1);
            if (lane == 0)  l  = 0.f;   // x = -1 zero pad
            if (lane == 63) rr = 0.f;   // x = 256 zero pad
            lft[r] = l; rgt[r] = rr;
        }

        float sim0 = 0.f, sim1 = 0.f, sim2 = 0.f, sim3 = 0.f;
        #pragma unroll
        for (int r = 0; r < 3; ++r) {
            const float w6_0 = lft[r];
            const float w6_1 = rowv[r].x;
            const float w6_2 = rowv[r].y;
            const float w6_3 = rowv[r].z;
            const float w6_4 = rowv[r].w;
            const float w6_5 = rgt[r];
            {
                const float4 k4 = kt[r * 3 + 0];   // j = 0
                sim0 = fmaf(w6_0, k4.x, sim0);
                sim1 = fmaf(w6_1, k4.y, sim1);
                sim2 = fmaf(w6_2, k4.z, sim2);
                sim3 = fmaf(w6_3, k4.w, sim3);
            }
            {
                const float4 k4 = kt[r * 3 + 1];   // j = 1
                sim0 = fmaf(w6_1, k4.x, sim0);
                sim1 = fmaf(w6_2, k4.y, sim1);
                sim2 = fmaf(w6_3, k4.z, sim2);
                sim3 = fmaf(w6_4, k4.w, sim3);
            }
            {
                const float4 k4 = kt[r * 3 + 2];   // j = 2
                sim0 = fmaf(w6_2, k4.x, sim0);
                sim1 = fmaf(w6_3, k4.y, sim1);
                sim2 = fmaf(w6_4, k4.z, sim2);
                sim3 = fmaf(w6_5, k4.w, sim3);
            }
        }

        f32x4 o;
        o.x = rowv[1].x * __builtin_amdgcn_rcpf(1.f + __expf(-sim0));
        o.y = rowv[1].y * __builtin_amdgcn_rcpf(1.f + __expf(-sim1));
        o.z = rowv[1].z * __builtin_amdgcn_rcpf(1.f + __expf(-sim2));
        o.w = rowv[1].w * __builtin_amdgcn_rcpf(1.f + __expf(-sim3));
        // non-temporal: out is never re-read; keep L2 for h-row halo reuse
        __builtin_nontemporal_store(o, (f32x4*)(out + ((size_t)(b * C_ + c) * H_ + y) * W_ + x0));
    }
}

extern "C" void kernel_launch(void* const* d_in, const int* in_sizes, int n_in,
                              void* d_out, int out_size, void* d_ws, size_t ws_size,
                              hipStream_t stream) {
    const float* lr  = (const float*)d_in[0];  // [8,3,256,256]
    const float* hin = (const float*)d_in[1];  // [8,64,256,256]
    const float* w1  = (const float*)d_in[2];  // [64,3,3,3]
    const float* b1  = (const float*)d_in[3];  // [64]
    const float* w2  = (const float*)d_in[4];  // [9,64,1,1]
    const float* b2  = (const float*)d_in[5];  // [9]
    float* out = (float*)d_out;                // [8,64,256,256]

    dim3 grid(B_ * H_);   // 2048 blocks
    dim3 block(256);
    hipLaunchKernelGGL(hsa_fused, grid, block, 0, stream,
                       lr, hin, w1, b1, w2, b2, out);
}

// Round 4
// 100.655 us; speedup vs baseline: 1.5521x; 1.5521x over previous
//
#include <hip/hip_runtime.h>
#include <hip/hip_bf16.h>
#include <math.h>

// Problem constants (from reference setup_inputs)
constexpr int B_  = 8;
constexpr int CIN = 3;
constexpr int C_  = 64;
constexpr int H_  = 256;
constexpr int W_  = 256;
constexpr int TAPS = 9;   // K*K, K=3

typedef float f32x4 __attribute__((ext_vector_type(4)));

// ============================================================================
// Kernel 1 (compute-bound): kern[b][y][t][x] = conv1x1(relu(conv3x3(lr)))
// One block per (b,y) row, thread = x pixel. ~2.4K FMA/thread, tiny memory.
// ============================================================================
__global__ __launch_bounds__(256, 4)
void hsa_kern(const float* __restrict__ lr,
              const float* __restrict__ w1,
              const float* __restrict__ b1,
              const float* __restrict__ w2,
              const float* __restrict__ b2,
              float* __restrict__ kws)
{
    __shared__ float w2t[C_][12];       // transposed 1x1 weights

    const int tid = threadIdx.x;
    const int blk = blockIdx.x;         // 0 .. B_*H_-1
    const int b = blk / H_;
    const int y = blk % H_;

    for (int i = tid; i < TAPS * C_; i += 256) {
        const int t = i / C_;
        const int c = i % C_;
        w2t[c][t] = w2[i];
    }
    __syncthreads();

    const int x = tid;                  // 0..255
    float win[CIN][3][3];
    #pragma unroll
    for (int ci = 0; ci < CIN; ++ci) {
        #pragma unroll
        for (int r = 0; r < 3; ++r) {
            const int yy = y + r - 1;
            const bool vy = (unsigned)yy < (unsigned)H_;
            const float* row = lr + ((size_t)(b * CIN + ci) * H_ + yy) * W_;
            win[ci][r][0] = (vy && x > 0)       ? row[x - 1] : 0.f;
            win[ci][r][1] = vy                   ? row[x]     : 0.f;
            win[ci][r][2] = (vy && x < W_ - 1)  ? row[x + 1] : 0.f;
        }
    }

    float acc[TAPS];
    #pragma unroll
    for (int t = 0; t < TAPS; ++t) acc[t] = b2[t];

    for (int c = 0; c < C_; ++c) {
        // conv1 (3x3, cin=3): three 9-deep chains (wave-uniform weights)
        const float* wc = w1 + c * 27;
        float h0 = b1[c], h1 = 0.f, h2 = 0.f;
        #pragma unroll
        for (int r = 0; r < 3; ++r)
            #pragma unroll
            for (int j = 0; j < 3; ++j) {
                h0 = fmaf(wc[(0 * 3 + r) * 3 + j], win[0][r][j], h0);
                h1 = fmaf(wc[(1 * 3 + r) * 3 + j], win[1][r][j], h1);
                h2 = fmaf(wc[(2 * 3 + r) * 3 + j], win[2][r][j], h2);
            }
        const float hsum = fmaxf((h0 + h1) + h2, 0.f);   // ReLU

        const float4 wa = *(const float4*)&w2t[c][0];
        const float4 wb = *(const float4*)&w2t[c][4];
        const float  w8 = w2t[c][8];
        acc[0] = fmaf(wa.x, hsum, acc[0]);
        acc[1] = fmaf(wa.y, hsum, acc[1]);
        acc[2] = fmaf(wa.z, hsum, acc[2]);
        acc[3] = fmaf(wa.w, hsum, acc[3]);
        acc[4] = fmaf(wb.x, hsum, acc[4]);
        acc[5] = fmaf(wb.y, hsum, acc[5]);
        acc[6] = fmaf(wb.z, hsum, acc[6]);
        acc[7] = fmaf(wb.w, hsum, acc[7]);
        acc[8] = fmaf(w8,  hsum, acc[8]);
    }

    // kws layout [b][y][t][x] -> 9 coalesced 1KB stores
    float* kr = kws + (size_t)(b * H_ + y) * TAPS * W_;
    #pragma unroll
    for (int t = 0; t < TAPS; ++t) kr[t * W_ + x] = acc[t];
}

// ============================================================================
// Kernel 2 (memory-bound): out = h * sigmoid(sum_taps shifted(h) * kern)
// One block per (b,y) row, XCD-swizzled so each XCD owns one batch with
// sequential y -> row-halo re-reads hit that XCD's private L2.
// Wave w handles channels [16w,16w+16); lane handles x0 = 4*lane.
// ============================================================================
__global__ __launch_bounds__(256, 8)
void hsa_gate(const float* __restrict__ hin,
              const float* __restrict__ kws,
              float* __restrict__ out)
{
    __shared__ float kernS[TAPS][W_];   // 9 KB

    const int tid = threadIdx.x;
    // bijective XCD swizzle: 2048 blocks = 8 XCDs x 256
    const int bid = blockIdx.x;
    const int nb  = (bid & 7) * (B_ * H_ / 8) + (bid >> 3);
    const int b = nb / H_;
    const int y = nb % H_;

    // stage kern row (contiguous 9 KB)
    const float* kr = kws + (size_t)(b * H_ + y) * TAPS * W_;
    for (int i = tid; i < TAPS * W_; i += 256)
        ((float*)kernS)[i] = kr[i];
    __syncthreads();

    const int lane = tid & 63;
    const int wav  = tid >> 6;
    const int x0   = lane * 4;

    float4 kt[TAPS];
    #pragma unroll
    for (int t = 0; t < TAPS; ++t) kt[t] = *(const float4*)&kernS[t][x0];

    #pragma unroll 4
    for (int cc = 0; cc < 16; ++cc) {
        const int c = wav * 16 + cc;
        const float* hb = hin + (size_t)(b * C_ + c) * H_ * W_;

        float4 rowv[3];
        float  lft[3], rgt[3];
        #pragma unroll
        for (int r = 0; r < 3; ++r) {
            const int yy = y + r - 1;
            const bool vy = (unsigned)yy < (unsigned)H_;
            float4 m;
            if (vy) m = *(const float4*)(hb + (size_t)yy * W_ + x0);
            else    m = make_float4(0.f, 0.f, 0.f, 0.f);
            rowv[r] = m;
            // column halo via cross-lane shuffle: one wave spans the full row
            float l  = __shfl_up(m.w, 1);
            float rr = __shfl_down(m.x, 1);
            if (lane == 0)  l  = 0.f;   // x = -1 zero pad
            if (lane == 63) rr = 0.f;   // x = 256 zero pad
            lft[r] = l; rgt[r] = rr;
        }

        float sim0 = 0.f, sim1 = 0.f, sim2 = 0.f, sim3 = 0.f;
        #pragma unroll
        for (int r = 0; r < 3; ++r) {
            const float w6_0 = lft[r];
            const float w6_1 = rowv[r].x;
            const float w6_2 = rowv[r].y;
            const float w6_3 = rowv[r].z;
            const float w6_4 = rowv[r].w;
            const float w6_5 = rgt[r];
            {
                const float4 k4 = kt[r * 3 + 0];   // j = 0
                sim0 = fmaf(w6_0, k4.x, sim0);
                sim1 = fmaf(w6_1, k4.y, sim1);
                sim2 = fmaf(w6_2, k4.z, sim2);
                sim3 = fmaf(w6_3, k4.w, sim3);
            }
            {
                const float4 k4 = kt[r * 3 + 1];   // j = 1
                sim0 = fmaf(w6_1, k4.x, sim0);
                sim1 = fmaf(w6_2, k4.y, sim1);
                sim2 = fmaf(w6_3, k4.z, sim2);
                sim3 = fmaf(w6_4, k4.w, sim3);
            }
            {
                const float4 k4 = kt[r * 3 + 2];   // j = 2
                sim0 = fmaf(w6_2, k4.x, sim0);
                sim1 = fmaf(w6_3, k4.y, sim1);
                sim2 = fmaf(w6_4, k4.z, sim2);
                sim3 = fmaf(w6_5, k4.w, sim3);
            }
        }

        f32x4 o;
        o.x = rowv[1].x * __builtin_amdgcn_rcpf(1.f + __expf(-sim0));
        o.y = rowv[1].y * __builtin_amdgcn_rcpf(1.f + __expf(-sim1));
        o.z = rowv[1].z * __builtin_amdgcn_rcpf(1.f + __expf(-sim2));
        o.w = rowv[1].w * __builtin_amdgcn_rcpf(1.f + __expf(-sim3));
        // non-temporal: out is never re-read; keep L2 for h-row halo reuse
        __builtin_nontemporal_store(o, (f32x4*)(out + ((size_t)(b * C_ + c) * H_ + y) * W_ + x0));
    }
}

// ============================================================================
// Fallback: R1 single fused kernel (used only if ws_size is too small)
// ============================================================================
__global__ __launch_bounds__(256, 4)
void hsa_fused(const float* __restrict__ lr,
               const float* __restrict__ hin,
               const float* __restrict__ w1,
               const float* __restrict__ b1,
               const float* __restrict__ w2,
               const float* __restrict__ b2,
               float* __restrict__ out)
{
    __shared__ float kernS[TAPS][W_];
    __shared__ float w2t[C_][12];

    const int tid = threadIdx.x;
    const int blk = blockIdx.x;
    const int b = blk / H_;
    const int y = blk % H_;

    for (int i = tid; i < TAPS * C_; i += 256) {
        const int t = i / C_;
        const int c = i % C_;
        w2t[c][t] = w2[i];
    }
    __syncthreads();

    {
        const int x = tid;
        float win[CIN][3][3];
        #pragma unroll
        for (int ci = 0; ci < CIN; ++ci)
            #pragma unroll
            for (int r = 0; r < 3; ++r) {
                const int yy = y + r - 1;
                const bool vy = (unsigned)yy < (unsigned)H_;
                const float* row = lr + ((size_t)(b * CIN + ci) * H_ + yy) * W_;
                win[ci][r][0] = (vy && x > 0)      ? row[x - 1] : 0.f;
                win[ci][r][1] = vy                  ? row[x]     : 0.f;
                win[ci][r][2] = (vy && x < W_ - 1) ? row[x + 1] : 0.f;
            }

        float acc[TAPS];
        #pragma unroll
        for (int t = 0; t < TAPS; ++t) acc[t] = b2[t];

        for (int c = 0; c < C_; ++c) {
            const float* wc = w1 + c * 27;
            float h0 = b1[c], h1 = 0.f, h2 = 0.f;
            #pragma unroll
            for (int r = 0; r < 3; ++r)
                #pragma unroll
                for (int j = 0; j < 3; ++j) {
                    h0 = fmaf(wc[(0 * 3 + r) * 3 + j], win[0][r][j], h0);
                    h1 = fmaf(wc[(1 * 3 + r) * 3 + j], win[1][r][j], h1);
                    h2 = fmaf(wc[(2 * 3 + r) * 3 + j], win[2][r][j], h2);
                }
            const float hsum = fmaxf((h0 + h1) + h2, 0.f);
            const float4 wa = *(const float4*)&w2t[c][0];
            const float4 wb = *(const float4*)&w2t[c][4];
            const float  w8 = w2t[c][8];
            acc[0] = fmaf(wa.x, hsum, acc[0]);
            acc[1] = fmaf(wa.y, hsum, acc[1]);
            acc[2] = fmaf(wa.z, hsum, acc[2]);
            acc[3] = fmaf(wa.w, hsum, acc[3]);
            acc[4] = fmaf(wb.x, hsum, acc[4]);
            acc[5] = fmaf(wb.y, hsum, acc[5]);
            acc[6] = fmaf(wb.z, hsum, acc[6]);
            acc[7] = fmaf(wb.w, hsum, acc[7]);
            acc[8] = fmaf(w8,  hsum, acc[8]);
        }
        #pragma unroll
        for (int t = 0; t < TAPS; ++t) kernS[t][x] = acc[t];
    }
    __syncthreads();

    const int lane = tid & 63;
    const int wav  = tid >> 6;
    const int x0   = lane * 4;

    float4 kt[TAPS];
    #pragma unroll
    for (int t = 0; t < TAPS; ++t) kt[t] = *(const float4*)&kernS[t][x0];

    #pragma unroll 4
    for (int cc = 0; cc < 16; ++cc) {
        const int c = wav * 16 + cc;
        const float* hb = hin + (size_t)(b * C_ + c) * H_ * W_;

        float4 rowv[3];
        float  lft[3], rgt[3];
        #pragma unroll
        for (int r = 0; r < 3; ++r) {
            const int yy = y + r - 1;
            const bool vy = (unsigned)yy < (unsigned)H_;
            float4 m;
            if (vy) m = *(const float4*)(hb + (size_t)yy * W_ + x0);
            else    m = make_float4(0.f, 0.f, 0.f, 0.f);
            rowv[r] = m;
            float l  = __shfl_up(m.w, 1);
            float rr = __shfl_down(m.x, 1);
            if (lane == 0)  l  = 0.f;
            if (lane == 63) rr = 0.f;
            lft[r] = l; rgt[r] = rr;
        }

        float sim0 = 0.f, sim1 = 0.f, sim2 = 0.f, sim3 = 0.f;
        #pragma unroll
        for (int r = 0; r < 3; ++r) {
            const float w6_0 = lft[r];
            const float w6_1 = rowv[r].x;
            const float w6_2 = rowv[r].y;
            const float w6_3 = rowv[r].z;
            const float w6_4 = rowv[r].w;
            const float w6_5 = rgt[r];
            { const float4 k4 = kt[r*3+0];
              sim0 = fmaf(w6_0, k4.x, sim0); sim1 = fmaf(w6_1, k4.y, sim1);
              sim2 = fmaf(w6_2, k4.z, sim2); sim3 = fmaf(w6_3, k4.w, sim3); }
            { const float4 k4 = kt[r*3+1];
              sim0 = fmaf(w6_1, k4.x, sim0); sim1 = fmaf(w6_2, k4.y, sim1);
              sim2 = fmaf(w6_3, k4.z, sim2); sim3 = fmaf(w6_4, k4.w, sim3); }
            { const float4 k4 = kt[r*3+2];
              sim0 = fmaf(w6_2, k4.x, sim0); sim1 = fmaf(w6_3, k4.y, sim1);
              sim2 = fmaf(w6_4, k4.z, sim2); sim3 = fmaf(w6_5, k4.w, sim3); }
        }

        float4 o;
        o.x = rowv[1].x * __builtin_amdgcn_rcpf(1.f + __expf(-sim0));
        o.y = rowv[1].y * __builtin_amdgcn_rcpf(1.f + __expf(-sim1));
        o.z = rowv[1].z * __builtin_amdgcn_rcpf(1.f + __expf(-sim2));
        o.w = rowv[1].w * __builtin_amdgcn_rcpf(1.f + __expf(-sim3));
        *(float4*)(out + ((size_t)(b * C_ + c) * H_ + y) * W_ + x0) = o;
    }
}

extern "C" void kernel_launch(void* const* d_in, const int* in_sizes, int n_in,
                              void* d_out, int out_size, void* d_ws, size_t ws_size,
                              hipStream_t stream) {
    const float* lr  = (const float*)d_in[0];  // [8,3,256,256]
    const float* hin = (const float*)d_in[1];  // [8,64,256,256]
    const float* w1  = (const float*)d_in[2];  // [64,3,3,3]
    const float* b1  = (const float*)d_in[3];  // [64]
    const float* w2  = (const float*)d_in[4];  // [9,64,1,1]
    const float* b2  = (const float*)d_in[5];  // [9]
    float* out = (float*)d_out;                // [8,64,256,256]

    const size_t kern_bytes = (size_t)B_ * H_ * TAPS * W_ * sizeof(float);

    if (ws_size >= kern_bytes) {
        float* kws = (float*)d_ws;
        hipLaunchKernelGGL(hsa_kern, dim3(B_ * H_), dim3(256), 0, stream,
                           lr, w1, b1, w2, b2, kws);
        hipLaunchKernelGGL(hsa_gate, dim3(B_ * H_), dim3(256), 0, stream,
                           hin, kws, out);
    } else {
        hipLaunchKernelGGL(hsa_fused, dim3(B_ * H_), dim3(256), 0, stream,
                           lr, hin, w1, b1, w2, b2, out);
    }
}